// Round 13
// baseline (497.029 us; speedup 1.0000x reference)
//
#include <hip/hip_runtime.h>
#include <float.h>
#include <math.h>

#define D 256
#define NROWS 65536
#define RPB 64
#define EPS_CAND 0.02f   // hi-only score error ~7 sigma + np quantization; candidates ~1.1/row
#define CAP 4            // max candidates per (dict,row); overflow -> full np-mimic fallback
#define WSFRAG 1024
#define WSKF   246784    // float offset of kfin ushort[1024*256] (within proven ws region)
#define WSDT   377856    // float offset of optional plain fp32 dicT[960][256]
#define ASTRIDE 520      // ushorts per (rt,s) LDS hi-fragment plane: 512 + 8 pad

// ws float layout:
//  [0..3]     alpha (float)
//  [4..963]   packed col norms ||c||^2, SEQUENTIAL UNFUSED fp32 (= numpy axis-0 reduce)
//  [968..975] 4 doubles: per-dict loss accumulators
//  [976..983] 4 doubles: alpha fp64
//  [1024..246784)    dict fragments: ushort[30 tiles][16 ksteps][2 splits][64 lanes][8]
//  [246784..377856)  kfin: ushort[1024 blocks][4 dicts][64 rows]
//  [377856..623616)  optional dicT[960][256] fp32 (guarded by ws_size)

typedef __attribute__((ext_vector_type(8)))  short short8v;
typedef __attribute__((ext_vector_type(16))) float f32x16;
typedef __attribute__((ext_vector_type(4)))  float float4v;
typedef __attribute__((ext_vector_type(4)))  uint  uint4v;

__device__ __forceinline__ ushort f2bf(float v) {
    uint u = __float_as_uint(v);
    u += 0x7fffu + ((u >> 16) & 1u);
    return (ushort)(u >> 16);
}
__device__ __forceinline__ float bf2f(ushort u) { return __uint_as_float(((uint)u) << 16); }

__device__ __forceinline__ int fidx(int ct, int c, int s, int half, int j, int p) {
    return ((ct * 16 + s) * 2 + p) * 512 + (c + 32 * half) * 8 + j;   // ws frag layout
}
__device__ __forceinline__ float dget(const ushort* fr, int pc, int d) {
    int b = fidx(pc >> 5, pc & 31, d >> 4, (d >> 3) & 1, d & 7, 0);
    return bf2f(fr[b]) + bf2f(fr[b + 512]);
}
__device__ __forceinline__ void dic_sel(int pc, const float* dc0, const float* dc1,
                                        const float* dc2, const float* dc3,
                                        const float*& dic, int& K, int& kk) {
    if      (pc < 64)  { dic = dc0; K = 64;  kk = pc;       }
    else if (pc < 192) { dic = dc1; K = 128; kk = pc - 64;  }
    else if (pc < 448) { dic = dc2; K = 256; kk = pc - 192; }
    else               { dic = dc3; K = 512; kk = pc - 448; }
}

__global__ void vq_prep(const float* __restrict__ av,
                        const float* __restrict__ dc0, const float* __restrict__ dc1,
                        const float* __restrict__ dc2, const float* __restrict__ dc3,
                        float* __restrict__ ws, float* __restrict__ dT)
{
    int t = blockIdx.x * 256 + threadIdx.x;
    ushort* fr = (ushort*)(ws + WSFRAG);
    if (t == 0) {
        double x0 = av[0], x1 = av[1], x2 = av[2], x3 = av[3];
        double m = fmax(fmax(x0, x1), fmax(x2, x3));
        double e0 = exp(x0 - m), e1 = exp(x1 - m), e2 = exp(x2 - m), e3 = exp(x3 - m);
        double inv = 1.0 / (e0 + e1 + e2 + e3);
        ws[0] = (float)(e0 * inv); ws[1] = (float)(e1 * inv);
        ws[2] = (float)(e2 * inv); ws[3] = (float)(e3 * inv);
        double* lacc = (double*)(ws + 968);
        lacc[0] = 0.0; lacc[1] = 0.0; lacc[2] = 0.0; lacc[3] = 0.0;
        double* dal = (double*)(ws + 976);
        dal[0] = e0 * inv; dal[1] = e1 * inv; dal[2] = e2 * inv; dal[3] = e3 * inv;
    }
    if (t < 960) {   // np-exact col norms (sequential unfused fp32) + optional fp32 dicT copy
        const float* dic; int K, kk;
        dic_sel(t, dc0, dc1, dc2, dc3, dic, K, kk);
        float s = 0.0f;
        if (dT != nullptr) {
            float* dr = dT + (size_t)t * D;
            for (int d = 0; d < D; ++d) {
                float v = dic[d * K + kk];
                s = __fadd_rn(s, __fmul_rn(v, v));
                dr[d] = v;
            }
        } else {
            for (int d = 0; d < D; ++d) {
                float v = dic[d * K + kk];
                s = __fadd_rn(s, __fmul_rn(v, v));
            }
        }
        ws[4 + t] = s;
    }
    if (t < 7680) {
        int pc = t >> 3;
        const float* dic; int K, kk;
        dic_sel(pc, dc0, dc1, dc2, dc3, dic, K, kk);
        int ct = pc >> 5, c = pc & 31;
        int kb = (t & 7) * 32;
        for (int k = kb; k < kb + 32; ++k) {
            float v = dic[k * K + kk];
            ushort hu = f2bf(v);
            ushort lu = f2bf(v - bf2f(hu));
            fr[fidx(ct, c, k >> 4, (k >> 3) & 1, k & 7, 0)] = hu;
            fr[fidx(ct, c, k >> 4, (k >> 3) & 1, k & 7, 1)] = lu;
        }
    }
}

__device__ __forceinline__ short8v load_B1(const ushort* bfr, int t, int s, int lane) {
    return *(const short8v*)&bfr[((t * 16 + s) * 2) * 512 + lane * 8];   // hi plane p=0
}
__device__ __forceinline__ void load_A1(short8v (&A)[2], const ushort* af, int s, int lane) {
    A[0] = *(const short8v*)&af[(0 * 16 + s) * ASTRIDE + lane * 8];
    A[1] = *(const short8v*)&af[(1 * 16 + s) * ASTRIDE + lane * 8];
}

// One pass over this wave's tiles [ts,te). 1 col-tile per step: 2 MFMA/kstep, acc = 32 AGPR.
// B: 4 buffers, prefetch distance 3 (MUST be <= buffers-1: write (s+3)&3 never aliases
// read s&3 — R12's distance-4 aliased and corrupted every kstep). Pipeline is continuous
// across tile boundaries. K-chain order per (rt, tile) unchanged -> scores bitwise stable.
template<class FE>
__device__ __forceinline__ void gemm_pass(const ushort* af, const ushort* bfr,
                                          int ts, int te, int lane, FE&& emit_tile)
{
    short8v A[2][2], B[4];
    load_A1(A[0], af, 0, lane);
    B[0] = load_B1(bfr, ts, 0, lane);
    B[1] = load_B1(bfr, ts, 1, lane);
    B[2] = load_B1(bfr, ts, 2, lane);
    for (int kt = ts; kt < te; ++kt) {
        f32x16 acc0 = (f32x16)(0.0f), acc1 = (f32x16)(0.0f);
#pragma unroll
        for (int s = 0; s < 16; ++s) {
            const int pt = kt + ((s + 3) >> 4);       // prefetch tile (compile-time per s)
            if (pt < te) B[(s + 3) & 3] = load_B1(bfr, pt, (s + 3) & 15, lane);
            load_A1(A[(s + 1) & 1], af, (s + 1) & 15, lane);
            acc0 = __builtin_amdgcn_mfma_f32_32x32x16_bf16(A[s & 1][0], B[s & 3], acc0, 0, 0, 0);
            acc1 = __builtin_amdgcn_mfma_f32_32x32x16_bf16(A[s & 1][1], B[s & 3], acc1, 0, 0, 0);
        }
        emit_tile(kt, acc0, acc1);
    }
}

__global__ void __launch_bounds__(256, 4) vq_score(
    const float* __restrict__ x,
    const float* __restrict__ dc0, const float* __restrict__ dc1,
    const float* __restrict__ dc2, const float* __restrict__ dc3,
    float* __restrict__ ws, const float* __restrict__ dT, ushort* __restrict__ wkf)
{
    __shared__ __align__(16) ushort afrag[32 * ASTRIDE];   // 33280 B
    __shared__ int   cand[4][64][CAP];                      // pass2; overlaid: slotmin[6][64] in pass1
    __shared__ float thrL[4][64];
    __shared__ float f2row[64];
    __shared__ int   cnt[4][64];
    __shared__ int   rep_list[64];
    __shared__ int   rep_cnt;

    float* slotminp = (float*)&cand[0][0][0];   // 384 floats <= 1024 ints; disjoint lifetime

    const int tid  = threadIdx.x;
    const int lane = tid & 63;
    const int wv   = __builtin_amdgcn_readfirstlane(tid >> 6);
    const int lcol = lane & 31, half = lane >> 5;
    const size_t rowbase = (size_t)blockIdx.x * RPB;

    if (tid == 0) rep_cnt = 0;
    for (int i = tid; i < 256; i += 256) (&cnt[0][0])[i] = 0;

    // ---- Stage A: x -> bf16 hi fragments (nt loads; b128 LDS writes) ----
    const float4v* x4 = (const float4v*)(x + rowbase * D);
    for (int it = 0; it < 8; ++it) {
        int f = it * 256 + tid;
        int row = f >> 5, sh = f & 31, s = sh >> 1, hf = sh & 1;
        float4v va = __builtin_nontemporal_load(&x4[row * 64 + s * 4 + hf * 2]);
        float4v vb = __builtin_nontemporal_load(&x4[row * 64 + s * 4 + hf * 2 + 1]);
        ushort h[8];
#pragma unroll
        for (int i = 0; i < 4; ++i) { h[i] = f2bf(va[i]); h[4 + i] = f2bf(vb[i]); }
        int bu = ((row >> 5) * 16 + s) * ASTRIDE + ((row & 31) + 32 * hf) * 8;
        uint4v Hv = { (uint)h[0] | ((uint)h[1] << 16), (uint)h[2] | ((uint)h[3] << 16),
                      (uint)h[4] | ((uint)h[5] << 16), (uint)h[6] | ((uint)h[7] << 16) };
        *(uint4v*)&afrag[bu] = Hv;
    }
    __syncthreads();

    // f2 per row from exact global x (fp64 -> fp32)
    if (tid < 64) {
        const float* xr = x + (rowbase + tid) * D;
        double s = 0.0;
        for (int d0 = 0; d0 < D; d0 += 4) {
            float4v v = *(const float4v*)&xr[d0];
#pragma unroll
            for (int j = 0; j < 4; ++j) s = fma((double)v[j], (double)v[j], s);
        }
        f2row[tid] = (float)s;
    }

    const ushort* bfr = (const ushort*)(ws + WSFRAG);
    const float*  c2g = ws + 4;
    // wave tile ranges: wv0: 0-6 (d0 t0-1, d1 t2-5, d2 t6), wv1: 7-13 (d2), wv2: 14-21 (d3), wv3: 22-29 (d3)
    const int ts = (wv == 0) ? 0 : (wv == 1) ? 7 : (wv == 2) ? 14 : 22;
    const int te = (wv == 0) ? 7 : (wv == 1) ? 14 : (wv == 2) ? 22 : 30;

    // ---- pass 1: per-(dict,row) min value ----
    {
        float rv0[16], rv1a[16];
#pragma unroll
        for (int r = 0; r < 16; ++r) { rv0[r] = FLT_MAX; rv1a[r] = FLT_MAX; }
        gemm_pass(afrag, bfr, ts, te, lane,
            [&](int kt, const f32x16& a0, const f32x16& a1) {
                const float c2t = c2g[kt * 32 + lcol];
#pragma unroll
                for (int reg = 0; reg < 16; ++reg) {
                    rv0[reg]  = fminf(rv0[reg],  fmaf(-2.0f, a0[reg], c2t));
                    rv1a[reg] = fminf(rv1a[reg], fmaf(-2.0f, a1[reg], c2t));
                }
                int slot = -1;   // dict-boundary flush tiles (wave-uniform branch)
                if      (kt == 1)  slot = 0;
                else if (kt == 5)  slot = 1;
                else if (kt == 6)  slot = 2;
                else if (kt == 13) slot = 3;
                else if (kt == 21) slot = 4;
                else if (kt == 29) slot = 5;
                if (slot >= 0) {
#pragma unroll
                    for (int rt = 0; rt < 2; ++rt)
#pragma unroll
                        for (int reg = 0; reg < 16; ++reg) {
                            float v = rt ? rv1a[reg] : rv0[reg];
#pragma unroll
                            for (int off = 1; off <= 16; off <<= 1) v = fminf(v, __shfl_xor(v, off));
                            if (lcol == reg)
                                slotminp[slot * 64 + rt * 32 + (reg & 3) + 8 * (reg >> 2) + 4 * half] = v;
                            if (rt) rv1a[reg] = FLT_MAX; else rv0[reg] = FLT_MAX;
                        }
                }
            });
    }
    __syncthreads();

    // combine slots -> threshold (d0:s0, d1:s1, d2:min(s2,s3), d3:min(s4,s5))
    {
        int i = tid >> 6, r = tid & 63;
        float m1 = (i == 0) ? slotminp[r]
                 : (i == 1) ? slotminp[64 + r]
                 : (i == 2) ? fminf(slotminp[128 + r], slotminp[192 + r])
                            : fminf(slotminp[256 + r], slotminp[320 + r]);
        thrL[i][r] = m1 + EPS_CAND;
    }
    __syncthreads();

    // ---- pass 2: recompute (bitwise same), collect candidates ----
    gemm_pass(afrag, bfr, ts, te, lane,
        [&](int kt, const f32x16& a0, const f32x16& a1) {
            const float c2t = c2g[kt * 32 + lcol];
            const int dct = (kt < 2) ? 0 : (kt < 6) ? 1 : (kt < 14) ? 2 : 3;
#pragma unroll
            for (int rt = 0; rt < 2; ++rt)
#pragma unroll
                for (int reg = 0; reg < 16; ++reg) {
                    float sc = fmaf(-2.0f, rt ? a1[reg] : a0[reg], c2t);
                    const int row = rt * 32 + (reg & 3) + 8 * (reg >> 2) + 4 * half;
                    if (sc < thrL[dct][row]) {
                        int pos = atomicAdd(&cnt[dct][row], 1);
                        if (pos < CAP) cand[dct][row][pos] = kt * 32 + lcol;
                    }
                }
        });
    __syncthreads();

    // ---- final select: np-mimic among candidates (thread = (dict,row)); write kfin to ws ----
    ushort* kf = wkf + (size_t)blockIdx.x * 256;
    {
        const int i = tid >> 6, r = tid & 63;
        const int n = cnt[i][r];
        if (n > CAP) {
            int p = atomicAdd(&rep_cnt, 1);
            rep_list[p] = (i << 6) | r;
        } else {
            const float f2 = f2row[r];
            const float* xrow = x + (rowbase + r) * D;
            float best = FLT_MAX; int bi = 0x7fffffff;
            for (int j = 0; j < n; ++j) {
                const int pc = cand[i][r][j];
                double smd = 0.0;
                if (dT != nullptr) {
                    const float* br = dT + (size_t)pc * D;
                    for (int d0 = 0; d0 < D; d0 += 4) {
                        float4v xa = *(const float4v*)&xrow[d0];
                        float4v bb = *(const float4v*)&br[d0];
#pragma unroll
                        for (int j2 = 0; j2 < 4; ++j2)
                            smd = fma((double)xa[j2], (double)bb[j2], smd);
                    }
                } else {
                    for (int d0 = 0; d0 < D; d0 += 8) {
                        float4v xa = *(const float4v*)&xrow[d0];
                        float4v xb = *(const float4v*)&xrow[d0 + 4];
                        int bb = fidx(pc >> 5, pc & 31, d0 >> 4, (d0 >> 3) & 1, 0, 0);
                        short8v bh = *(const short8v*)&bfr[bb];
                        short8v bl = *(const short8v*)&bfr[bb + 512];
#pragma unroll
                        for (int j2 = 0; j2 < 4; ++j2) {
                            double bv0 = (double)(bf2f((ushort)bh[j2]) + bf2f((ushort)bl[j2]));
                            double bv1 = (double)(bf2f((ushort)bh[4 + j2]) + bf2f((ushort)bl[4 + j2]));
                            smd = fma((double)xa[j2], bv0, smd);
                            smd = fma((double)xb[j2], bv1, smd);
                        }
                    }
                }
                float sim  = (float)smd;
                float dist = __fsub_rn(__fadd_rn(f2, c2g[pc]), __fmul_rn(2.0f, sim));
                if (dist < best || (dist == best && pc < bi)) { best = dist; bi = pc; }
            }
            kf[i * 64 + r] = (ushort)bi;
        }
    }
    __syncthreads();

    // ---- rare fallback: full np-mimic scan (one wave per overflowed pair) ----
    for (int t = wv; t < rep_cnt; t += 4) {
        int e = rep_list[t];
        int i = e >> 6, r = e & 63;
        const float* dic; int K, base;
        if      (i == 0) { dic = dc0; K = 64;  base = 0;   }
        else if (i == 1) { dic = dc1; K = 128; base = 64;  }
        else if (i == 2) { dic = dc2; K = 256; base = 192; }
        else             { dic = dc3; K = 512; base = 448; }
        const float* xrow = x + (rowbase + r) * D;
        const float f2 = f2row[r];
        float bestv = FLT_MAX; int besti = 0x7fffffff;
        for (int c = lane; c < K; c += 64) {
            float  cn  = 0.0f;
            double smd = 0.0;
            for (int d = 0; d < D; ++d) {
                float bv = dic[d * K + c];
                cn  = __fadd_rn(cn, __fmul_rn(bv, bv));
                smd = fma((double)xrow[d], (double)bv, smd);
            }
            float sim  = (float)smd;
            float dist = __fsub_rn(__fadd_rn(f2, cn), __fmul_rn(2.0f, sim));
            if (dist < bestv) { bestv = dist; besti = c; }
        }
#pragma unroll
        for (int off = 32; off; off >>= 1) {
            float ov = __shfl_xor(bestv, off);
            int   oi = __shfl_xor(besti, off);
            if (ov < bestv || (ov == bestv && oi < besti)) { bestv = ov; besti = oi; }
        }
        if (lane == 0) kf[i * 64 + r] = (ushort)(base + besti);
    }
}

__global__ void vq_epi(const float* __restrict__ x, float* __restrict__ ws,
                       const float* __restrict__ dT, const ushort* __restrict__ wkf,
                       float* __restrict__ out)
{
    __shared__ double lred[4][4];
    __shared__ int kf[256];

    const int tid  = threadIdx.x;
    const int lane = tid & 63;
    const int wv   = __builtin_amdgcn_readfirstlane(tid >> 6);
    const size_t rowbase = (size_t)blockIdx.x * RPB;
    const ushort* bfr = (const ushort*)(ws + WSFRAG);

    kf[tid] = wkf[(size_t)blockIdx.x * 256 + tid];
    __syncthreads();

    const float a0 = ws[0], a1 = ws[1], a2 = ws[2], a3 = ws[3];
    double l0 = 0.0, l1 = 0.0, l2 = 0.0, l3 = 0.0;
#pragma unroll 4
    for (int r = 0; r < RPB; ++r) {
        const float xv = __builtin_nontemporal_load(&x[(rowbase + r) * D + tid]);
        const int i0 = kf[r], i1 = kf[64 + r], i2 = kf[128 + r], i3 = kf[192 + r];
        float q0, q1, q2, q3;
        if (dT != nullptr) {
            q0 = dT[(size_t)i0 * D + tid];
            q1 = dT[(size_t)i1 * D + tid];
            q2 = dT[(size_t)i2 * D + tid];
            q3 = dT[(size_t)i3 * D + tid];
        } else {
            q0 = dget(bfr, i0, tid);
            q1 = dget(bfr, i1, tid);
            q2 = dget(bfr, i2, tid);
            q3 = dget(bfr, i3, tid);
        }
        float wq = __fadd_rn(__fadd_rn(__fadd_rn(__fmul_rn(a0, q0), __fmul_rn(a1, q1)),
                                       __fmul_rn(a2, q2)), __fmul_rn(a3, q3));
        __builtin_nontemporal_store(__fadd_rn(xv, __fsub_rn(wq, xv)),
                                    &out[(rowbase + r) * D + tid]);
        const float e0 = xv - q0, e1 = xv - q1, e2 = xv - q2, e3 = xv - q3;
        l0 = fma((double)e0, (double)e0, l0);
        l1 = fma((double)e1, (double)e1, l1);
        l2 = fma((double)e2, (double)e2, l2);
        l3 = fma((double)e3, (double)e3, l3);
    }
#pragma unroll
    for (int off = 32; off; off >>= 1) {
        l0 += __shfl_down(l0, off); l1 += __shfl_down(l1, off);
        l2 += __shfl_down(l2, off); l3 += __shfl_down(l3, off);
    }
    if (lane == 0) { lred[wv][0] = l0; lred[wv][1] = l1; lred[wv][2] = l2; lred[wv][3] = l3; }
    __syncthreads();
    if (tid == 0) {
        double* lacc = (double*)(ws + 968);
#pragma unroll
        for (int i = 0; i < 4; ++i)
            atomicAdd(lacc + i, lred[0][i] + lred[1][i] + lred[2][i] + lred[3][i]);
    }
}

__global__ void vq_fin(const float* __restrict__ ws, float* __restrict__ out)
{
    if (threadIdx.x == 0) {
        const double* lacc = (const double*)(ws + 968);
        const double* dal  = (const double*)(ws + 976);
        double s = 0.0;
#pragma unroll
        for (int i = 0; i < 4; ++i) s += (lacc[i] * (1.0 / 16777216.0)) * dal[i];
        out[16777216] = (float)(s + 0.25 * s);
    }
}

extern "C" void kernel_launch(void* const* d_in, const int* in_sizes, int n_in,
                              void* d_out, int out_size, void* d_ws, size_t ws_size,
                              hipStream_t stream)
{
    const float* x   = (const float*)d_in[0];
    const float* av  = (const float*)d_in[1];
    const float* dc0 = (const float*)d_in[2];
    const float* dc1 = (const float*)d_in[3];
    const float* dc2 = (const float*)d_in[4];
    const float* dc3 = (const float*)d_in[5];
    float* out = (float*)d_out;
    float* ws  = (float*)d_ws;

    ushort* wkf = (ushort*)(ws + WSKF);   // within proven ws region
    const bool haveDT = ws_size >= (size_t)(WSDT + 960 * 256) * sizeof(float);
    float* dT = haveDT ? (ws + WSDT) : nullptr;

    hipLaunchKernelGGL(vq_prep, dim3(30), dim3(256), 0, stream, av, dc0, dc1, dc2, dc3, ws, dT);
    hipLaunchKernelGGL(vq_score, dim3(NROWS / RPB), dim3(256), 0, stream,
                       x, dc0, dc1, dc2, dc3, ws, dT, wkf);
    hipLaunchKernelGGL(vq_epi, dim3(NROWS / RPB), dim3(256), 0, stream, x, ws, dT, wkf, out);
    hipLaunchKernelGGL(vq_fin, dim3(1), dim3(64), 0, stream, ws, out);
}

// Round 14
// 376.351 us; speedup vs baseline: 1.3207x; 1.3207x over previous
//
#include <hip/hip_runtime.h>
#include <float.h>
#include <math.h>

#define D 256
#define NROWS 65536
#define RPB 128               // rows per score/epi block
#define NBLK (NROWS / RPB)    // 512
#define NT 30                 // packed col tiles
#define EPS_CAND 0.02f        // hi-only score error ~7 sigma + np quantization
#define CAP 4
#define WSFRAG 1024
#define WSKF   246784         // kfin ushort[512 blocks][4 dicts][128 rows] = 512KB
#define WSDT   377856         // optional fp32 dicT[960][256]
#define ASTRIDE 520

// smem byte map (single buffer, phase-disjoint overlays):
//  [0,32768)      B double buffer (2 x 16 KB)         | overlaid by afrag [0,33280) in A-stage phase
//  [32768,34816)  thrL float[4][128]                  | (tail overlaps afrag; written post-A-stage)
//  [34816,35328)  f2row float[128]
//  [35328,37376)  cnt int[4][128]
//  [37376,45568)  cand int[4][128][CAP]
//  [45568,47616)  rep_list int[512]
//  [47616,47620)  rep_cnt
#define SM_B    0
#define SM_THR  32768
#define SM_F2   34816
#define SM_CNT  35328
#define SM_CAND 37376
#define SM_REP  45568
#define SM_REPC 47616
#define SM_TOT  47632

typedef __attribute__((ext_vector_type(8)))  short short8v;
typedef __attribute__((ext_vector_type(16))) float f32x16;
typedef __attribute__((ext_vector_type(4)))  float float4v;
typedef __attribute__((ext_vector_type(4)))  uint  uint4v;

__device__ __forceinline__ ushort f2bf(float v) {
    uint u = __float_as_uint(v);
    u += 0x7fffu + ((u >> 16) & 1u);
    return (ushort)(u >> 16);
}
__device__ __forceinline__ float bf2f(ushort u) { return __uint_as_float(((uint)u) << 16); }

__device__ __forceinline__ int fidx(int ct, int c, int s, int half, int j, int p) {
    return ((ct * 16 + s) * 2 + p) * 512 + (c + 32 * half) * 8 + j;   // ws frag layout
}
__device__ __forceinline__ float dget(const ushort* fr, int pc, int d) {
    int b = fidx(pc >> 5, pc & 31, d >> 4, (d >> 3) & 1, d & 7, 0);
    return bf2f(fr[b]) + bf2f(fr[b + 512]);
}
__device__ __forceinline__ void dic_sel(int pc, const float* dc0, const float* dc1,
                                        const float* dc2, const float* dc3,
                                        const float*& dic, int& K, int& kk) {
    if      (pc < 64)  { dic = dc0; K = 64;  kk = pc;       }
    else if (pc < 192) { dic = dc1; K = 128; kk = pc - 64;  }
    else if (pc < 448) { dic = dc2; K = 256; kk = pc - 192; }
    else               { dic = dc3; K = 512; kk = pc - 448; }
}

__global__ void vq_prep(const float* __restrict__ av,
                        const float* __restrict__ dc0, const float* __restrict__ dc1,
                        const float* __restrict__ dc2, const float* __restrict__ dc3,
                        float* __restrict__ ws, float* __restrict__ dT)
{
    int t = blockIdx.x * 256 + threadIdx.x;
    ushort* fr = (ushort*)(ws + WSFRAG);
    if (t == 0) {
        double x0 = av[0], x1 = av[1], x2 = av[2], x3 = av[3];
        double m = fmax(fmax(x0, x1), fmax(x2, x3));
        double e0 = exp(x0 - m), e1 = exp(x1 - m), e2 = exp(x2 - m), e3 = exp(x3 - m);
        double inv = 1.0 / (e0 + e1 + e2 + e3);
        ws[0] = (float)(e0 * inv); ws[1] = (float)(e1 * inv);
        ws[2] = (float)(e2 * inv); ws[3] = (float)(e3 * inv);
        double* lacc = (double*)(ws + 968);
        lacc[0] = 0.0; lacc[1] = 0.0; lacc[2] = 0.0; lacc[3] = 0.0;
        double* dal = (double*)(ws + 976);
        dal[0] = e0 * inv; dal[1] = e1 * inv; dal[2] = e2 * inv; dal[3] = e3 * inv;
    }
    if (t < 960) {
        const float* dic; int K, kk;
        dic_sel(t, dc0, dc1, dc2, dc3, dic, K, kk);
        float s = 0.0f;
        if (dT != nullptr) {
            float* dr = dT + (size_t)t * D;
            for (int d = 0; d < D; ++d) {
                float v = dic[d * K + kk];
                s = __fadd_rn(s, __fmul_rn(v, v));
                dr[d] = v;
            }
        } else {
            for (int d = 0; d < D; ++d) {
                float v = dic[d * K + kk];
                s = __fadd_rn(s, __fmul_rn(v, v));
            }
        }
        ws[4 + t] = s;
    }
    if (t < 7680) {
        int pc = t >> 3;
        const float* dic; int K, kk;
        dic_sel(pc, dc0, dc1, dc2, dc3, dic, K, kk);
        int ct = pc >> 5, c = pc & 31;
        int kb = (t & 7) * 32;
        for (int k = kb; k < kb + 32; ++k) {
            float v = dic[k * K + kk];
            ushort hu = f2bf(v);
            ushort lu = f2bf(v - bf2f(hu));
            fr[fidx(ct, c, k >> 4, (k >> 3) & 1, k & 7, 0)] = hu;
            fr[fidx(ct, c, k >> 4, (k >> 3) & 1, k & 7, 1)] = lu;
        }
    }
}

__global__ void __launch_bounds__(256, 2) vq_score(
    const float* __restrict__ x,
    const float* __restrict__ dc0, const float* __restrict__ dc1,
    const float* __restrict__ dc2, const float* __restrict__ dc3,
    float* __restrict__ ws, const float* __restrict__ dT, ushort* __restrict__ wkf)
{
    __shared__ __align__(16) char smem[SM_TOT];
    float (*thrL)[128]      = (float(*)[128])(smem + SM_THR);
    float*  f2row           = (float*)(smem + SM_F2);
    int (*cnt)[128]         = (int(*)[128])(smem + SM_CNT);
    int (*cand)[128][CAP]   = (int(*)[128][CAP])(smem + SM_CAND);
    int* rep_list           = (int*)(smem + SM_REP);
    int* rep_cnt            = (int*)(smem + SM_REPC);

    const int tid  = threadIdx.x;
    const int lane = tid & 63;
    const int wv   = __builtin_amdgcn_readfirstlane(tid >> 6);
    const int lcol = lane & 31, half = lane >> 5;
    const size_t rowbase = (size_t)blockIdx.x * RPB;
    const int rb32 = wv * 32;     // this wave's block-local row base

    if (tid == 0) *rep_cnt = 0;
    for (int i = tid; i < 512; i += 256) (&cnt[0][0])[i] = 0;

    // ---- A stage: 2 rounds of 64 rows via LDS (coalesced), then A lives in 64 VGPR/wave ----
    ushort* afrag = (ushort*)smem;     // [2 rt][16 s][520] transient, overlays B region
    short8v A[16];
    for (int rnd = 0; rnd < 2; ++rnd) {
        const float4v* x4 = (const float4v*)(x + (rowbase + rnd * 64) * D);
        for (int it = 0; it < 8; ++it) {
            int f = it * 256 + tid;
            int row = f >> 5, sh = f & 31, s = sh >> 1, hf = sh & 1;
            float4v va = __builtin_nontemporal_load(&x4[row * 64 + s * 4 + hf * 2]);
            float4v vb = __builtin_nontemporal_load(&x4[row * 64 + s * 4 + hf * 2 + 1]);
            ushort h[8];
#pragma unroll
            for (int i = 0; i < 4; ++i) { h[i] = f2bf(va[i]); h[4 + i] = f2bf(vb[i]); }
            int bu = ((row >> 5) * 16 + s) * ASTRIDE + ((row & 31) + 32 * hf) * 8;
            uint4v Hv = { (uint)h[0] | ((uint)h[1] << 16), (uint)h[2] | ((uint)h[3] << 16),
                          (uint)h[4] | ((uint)h[5] << 16), (uint)h[6] | ((uint)h[7] << 16) };
            *(uint4v*)&afrag[bu] = Hv;
        }
        __syncthreads();
        if ((wv >> 1) == rnd) {
            const int rtl = wv & 1;
#pragma unroll
            for (int s = 0; s < 16; ++s)
                A[s] = *(const short8v*)&afrag[(rtl * 16 + s) * ASTRIDE + lane * 8];
        }
        __syncthreads();
    }

    // f2 per row from exact global x (fp64 -> fp32)
    if (tid < 128) {
        const float* xr = x + (rowbase + tid) * D;
        double s = 0.0;
        for (int d0 = 0; d0 < D; d0 += 4) {
            float4v v = *(const float4v*)&xr[d0];
#pragma unroll
            for (int j = 0; j < 4; ++j) s = fma((double)v[j], (double)v[j], s);
        }
        f2row[tid] = (float)s;
    }

    const ushort* bfr = (const ushort*)(ws + WSFRAG);
    const float*  c2g = ws + 4;

    // B tile staging helpers: wave wv stages ksteps {4wv..4wv+3} (16B per lane each)
    auto gload = [&](uint4v (&T)[4], int t) {
#pragma unroll
        for (int i = 0; i < 4; ++i) {
            const int s = wv * 4 + i;
            T[i] = *(const uint4v*)&bfr[((t * 16 + s) * 2) * 512 + lane * 8];
        }
    };
    auto dswr = [&](const uint4v (&T)[4], char* buf) {
#pragma unroll
        for (int i = 0; i < 4; ++i) {
            const int s = wv * 4 + i;
            *(uint4v*)(buf + s * 1024 + (size_t)lane * 16) = T[i];
        }
    };

    // pipeline: gload(next) -> compute(cur from LDS) -> dswr(next) -> barrier  (T14 split)
    auto run_pass = [&](auto&& emit) {
        uint4v T[4];
        gload(T, 0);
        dswr(T, smem + SM_B);
        __syncthreads();
        for (int kt = 0; kt < NT; ++kt) {
            const char* bufc = smem + SM_B + (kt & 1) * 16384;
            if (kt < NT - 1) gload(T, kt + 1);
            f32x16 ae = (f32x16)(0.0f), ao = (f32x16)(0.0f);
#pragma unroll
            for (int s = 0; s < 16; ++s) {
                short8v Bs = *(const short8v*)(bufc + s * 1024 + (size_t)lane * 16);
                if (s & 1) ao = __builtin_amdgcn_mfma_f32_32x32x16_bf16(A[s], Bs, ao, 0, 0, 0);
                else       ae = __builtin_amdgcn_mfma_f32_32x32x16_bf16(A[s], Bs, ae, 0, 0, 0);
            }
            emit(kt, ae, ao);
            if (kt < NT - 1) dswr(T, smem + SM_B + ((kt + 1) & 1) * 16384);
            __syncthreads();
        }
    };

    // ---- pass 1: per-(dict,row) min -> thrL (wave owns its 32 rows exclusively) ----
    {
        float rv[16];
#pragma unroll
        for (int r = 0; r < 16; ++r) rv[r] = FLT_MAX;
        run_pass([&](int kt, const f32x16& ae, const f32x16& ao) {
            const float c2t = c2g[kt * 32 + lcol];
#pragma unroll
            for (int r = 0; r < 16; ++r)
                rv[r] = fminf(rv[r], fmaf(-2.0f, ae[r] + ao[r], c2t));
            if (kt == 1 || kt == 5 || kt == 13 || kt == 29) {   // dict-end tiles
                const int dct = (kt == 1) ? 0 : (kt == 5) ? 1 : (kt == 13) ? 2 : 3;
#pragma unroll
                for (int r = 0; r < 16; ++r) {
                    float v = rv[r];
#pragma unroll
                    for (int off = 1; off <= 16; off <<= 1) v = fminf(v, __shfl_xor(v, off));
                    if (lcol == r)
                        thrL[dct][rb32 + (r & 3) + 8 * (r >> 2) + 4 * half] = v + EPS_CAND;
                    rv[r] = FLT_MAX;
                }
            }
        });
    }
    __syncthreads();

    // ---- pass 2: recompute (bitwise same), collect candidates ----
    run_pass([&](int kt, const f32x16& ae, const f32x16& ao) {
        const float c2t = c2g[kt * 32 + lcol];
        const int dct = (kt < 2) ? 0 : (kt < 6) ? 1 : (kt < 14) ? 2 : 3;
#pragma unroll
        for (int r = 0; r < 16; ++r) {
            float sc = fmaf(-2.0f, ae[r] + ao[r], c2t);
            const int row = rb32 + (r & 3) + 8 * (r >> 2) + 4 * half;
            if (sc < thrL[dct][row]) {
                int pos = atomicAdd(&cnt[dct][row], 1);
                if (pos < CAP) cand[dct][row][pos] = kt * 32 + lcol;
            }
        }
    });
    __syncthreads();

    // ---- final select: np-mimic among candidates; 512 (dict,row) pairs over 256 threads ----
    ushort* kf = wkf + (size_t)blockIdx.x * 512;
    for (int p = tid; p < 512; p += 256) {
        const int i = p >> 7, r = p & 127;
        const int n = cnt[i][r];
        if (n > CAP) {
            int q = atomicAdd(rep_cnt, 1);
            rep_list[q] = p;
        } else {
            const float f2 = f2row[r];
            const float* xrow = x + (rowbase + r) * D;
            float best = FLT_MAX; int bi = 0x7fffffff;
            for (int j = 0; j < n; ++j) {
                const int pc = cand[i][r][j];
                double smd = 0.0;
                if (dT != nullptr) {
                    const float* br = dT + (size_t)pc * D;
                    for (int d0 = 0; d0 < D; d0 += 4) {
                        float4v xa = *(const float4v*)&xrow[d0];
                        float4v bb = *(const float4v*)&br[d0];
#pragma unroll
                        for (int j2 = 0; j2 < 4; ++j2)
                            smd = fma((double)xa[j2], (double)bb[j2], smd);
                    }
                } else {
                    for (int d0 = 0; d0 < D; d0 += 8) {
                        float4v xa = *(const float4v*)&xrow[d0];
                        float4v xb = *(const float4v*)&xrow[d0 + 4];
                        int bb = fidx(pc >> 5, pc & 31, d0 >> 4, (d0 >> 3) & 1, 0, 0);
                        short8v bh = *(const short8v*)&bfr[bb];
                        short8v bl = *(const short8v*)&bfr[bb + 512];
#pragma unroll
                        for (int j2 = 0; j2 < 4; ++j2) {
                            double bv0 = (double)(bf2f((ushort)bh[j2]) + bf2f((ushort)bl[j2]));
                            double bv1 = (double)(bf2f((ushort)bh[4 + j2]) + bf2f((ushort)bl[4 + j2]));
                            smd = fma((double)xa[j2], bv0, smd);
                            smd = fma((double)xb[j2], bv1, smd);
                        }
                    }
                }
                float sim  = (float)smd;
                float dist = __fsub_rn(__fadd_rn(f2, c2g[pc]), __fmul_rn(2.0f, sim));
                if (dist < best || (dist == best && pc < bi)) { best = dist; bi = pc; }
            }
            kf[i * 128 + r] = (ushort)bi;
        }
    }
    __syncthreads();

    // ---- rare fallback: full np-mimic scan (one wave per overflowed pair) ----
    for (int t = wv; t < *rep_cnt; t += 4) {
        int e = rep_list[t];
        int i = e >> 7, r = e & 127;
        const float* dic; int K, base;
        if      (i == 0) { dic = dc0; K = 64;  base = 0;   }
        else if (i == 1) { dic = dc1; K = 128; base = 64;  }
        else if (i == 2) { dic = dc2; K = 256; base = 192; }
        else             { dic = dc3; K = 512; base = 448; }
        const float* xrow = x + (rowbase + r) * D;
        const float f2 = f2row[r];
        float bestv = FLT_MAX; int besti = 0x7fffffff;
        for (int c = lane; c < K; c += 64) {
            float  cn  = 0.0f;
            double smd = 0.0;
            for (int d = 0; d < D; ++d) {
                float bv = dic[d * K + c];
                cn  = __fadd_rn(cn, __fmul_rn(bv, bv));
                smd = fma((double)xrow[d], (double)bv, smd);
            }
            float sim  = (float)smd;
            float dist = __fsub_rn(__fadd_rn(f2, cn), __fmul_rn(2.0f, sim));
            if (dist < bestv) { bestv = dist; besti = c; }
        }
#pragma unroll
        for (int off = 32; off; off >>= 1) {
            float ov = __shfl_xor(bestv, off);
            int   oi = __shfl_xor(besti, off);
            if (ov < bestv || (ov == bestv && oi < besti)) { bestv = ov; besti = oi; }
        }
        if (lane == 0) kf[i * 128 + r] = (ushort)(base + besti);
    }
}

__global__ void vq_epi(const float* __restrict__ x, float* __restrict__ ws,
                       const float* __restrict__ dT, const ushort* __restrict__ wkf,
                       float* __restrict__ out)
{
    __shared__ double lred[4][4];
    __shared__ int kf[512];

    const int tid  = threadIdx.x;
    const int lane = tid & 63;
    const int wv   = __builtin_amdgcn_readfirstlane(tid >> 6);
    const size_t rowbase = (size_t)blockIdx.x * RPB;
    const ushort* bfr = (const ushort*)(ws + WSFRAG);

    kf[tid]       = wkf[(size_t)blockIdx.x * 512 + tid];
    kf[256 + tid] = wkf[(size_t)blockIdx.x * 512 + 256 + tid];
    __syncthreads();

    const float a0 = ws[0], a1 = ws[1], a2 = ws[2], a3 = ws[3];
    double l0 = 0.0, l1 = 0.0, l2 = 0.0, l3 = 0.0;
#pragma unroll 4
    for (int r = 0; r < RPB; ++r) {
        const float xv = __builtin_nontemporal_load(&x[(rowbase + r) * D + tid]);
        const int i0 = kf[r], i1 = kf[128 + r], i2 = kf[256 + r], i3 = kf[384 + r];
        float q0, q1, q2, q3;
        if (dT != nullptr) {
            q0 = dT[(size_t)i0 * D + tid];
            q1 = dT[(size_t)i1 * D + tid];
            q2 = dT[(size_t)i2 * D + tid];
            q3 = dT[(size_t)i3 * D + tid];
        } else {
            q0 = dget(bfr, i0, tid);
            q1 = dget(bfr, i1, tid);
            q2 = dget(bfr, i2, tid);
            q3 = dget(bfr, i3, tid);
        }
        float wq = __fadd_rn(__fadd_rn(__fadd_rn(__fmul_rn(a0, q0), __fmul_rn(a1, q1)),
                                       __fmul_rn(a2, q2)), __fmul_rn(a3, q3));
        __builtin_nontemporal_store(__fadd_rn(xv, __fsub_rn(wq, xv)),
                                    &out[(rowbase + r) * D + tid]);
        const float e0 = xv - q0, e1 = xv - q1, e2 = xv - q2, e3 = xv - q3;
        l0 = fma((double)e0, (double)e0, l0);
        l1 = fma((double)e1, (double)e1, l1);
        l2 = fma((double)e2, (double)e2, l2);
        l3 = fma((double)e3, (double)e3, l3);
    }
#pragma unroll
    for (int off = 32; off; off >>= 1) {
        l0 += __shfl_down(l0, off); l1 += __shfl_down(l1, off);
        l2 += __shfl_down(l2, off); l3 += __shfl_down(l3, off);
    }
    if (lane == 0) { lred[wv][0] = l0; lred[wv][1] = l1; lred[wv][2] = l2; lred[wv][3] = l3; }
    __syncthreads();
    if (tid == 0) {
        double* lacc = (double*)(ws + 968);
#pragma unroll
        for (int i = 0; i < 4; ++i)
            atomicAdd(lacc + i, lred[0][i] + lred[1][i] + lred[2][i] + lred[3][i]);
    }
}

__global__ void vq_fin(const float* __restrict__ ws, float* __restrict__ out)
{
    if (threadIdx.x == 0) {
        const double* lacc = (const double*)(ws + 968);
        const double* dal  = (const double*)(ws + 976);
        double s = 0.0;
#pragma unroll
        for (int i = 0; i < 4; ++i) s += (lacc[i] * (1.0 / 16777216.0)) * dal[i];
        out[16777216] = (float)(s + 0.25 * s);
    }
}

extern "C" void kernel_launch(void* const* d_in, const int* in_sizes, int n_in,
                              void* d_out, int out_size, void* d_ws, size_t ws_size,
                              hipStream_t stream)
{
    const float* x   = (const float*)d_in[0];
    const float* av  = (const float*)d_in[1];
    const float* dc0 = (const float*)d_in[2];
    const float* dc1 = (const float*)d_in[3];
    const float* dc2 = (const float*)d_in[4];
    const float* dc3 = (const float*)d_in[5];
    float* out = (float*)d_out;
    float* ws  = (float*)d_ws;

    ushort* wkf = (ushort*)(ws + WSKF);
    const bool haveDT = ws_size >= (size_t)(WSDT + 960 * 256) * sizeof(float);
    float* dT = haveDT ? (ws + WSDT) : nullptr;

    hipLaunchKernelGGL(vq_prep, dim3(30), dim3(256), 0, stream, av, dc0, dc1, dc2, dc3, ws, dT);
    hipLaunchKernelGGL(vq_score, dim3(NBLK), dim3(256), 0, stream,
                       x, dc0, dc1, dc2, dc3, ws, dT, wkf);
    hipLaunchKernelGGL(vq_epi, dim3(NBLK), dim3(256), 0, stream, x, ws, dT, wkf, out);
    hipLaunchKernelGGL(vq_fin, dim3(1), dim3(64), 0, stream, ws, out);
}